// Round 7
// baseline (114.401 us; speedup 1.0000x reference)
//
#include <hip/hip_runtime.h>
#include <hip/hip_bf16.h>

#define IN_CH 256
#define OUT_CH 256
#define LATENT 512
#define MSCALE (1.0f / 16.0f)   // 1/sqrt(256)

typedef __attribute__((ext_vector_type(8)))  short bf16x8;
typedef __attribute__((ext_vector_type(16))) float f32x16;
typedef unsigned short u16;

__device__ __forceinline__ u16 f2bf(float f) {
  unsigned int x = __float_as_uint(f);
  x += 0x7fffu + ((x >> 16) & 1u);   // round-to-nearest-even
  return (u16)(x >> 16);
}

// async global->LDS, 16B/lane; LDS dst is wave-uniform base + lane*16.
__device__ __forceinline__ void gload_lds16(const u16* g, u16* l) {
#if defined(__has_builtin) && __has_builtin(__builtin_amdgcn_global_load_lds)
  __builtin_amdgcn_global_load_lds(
      (const __attribute__((address_space(1))) unsigned int*)g,
      (__attribute__((address_space(3))) unsigned int*)l, 16, 0, 0);
#else
  int lane = __builtin_amdgcn_mbcnt_hi(~0u, __builtin_amdgcn_mbcnt_lo(~0u, 0));
  ((uint4*)l)[lane] = *(const uint4*)g;
#endif
}

// ---- kernel 1: mod[b][i]=(1+style)*SCALE ; demod[b][o]=rsqrt(sum mod^2*wsq) --
__global__ void k_style_demod(const float* __restrict__ w, const float* __restrict__ sw,
                              const float* __restrict__ sb, const float* __restrict__ wsq,
                              float* __restrict__ mod, float* __restrict__ demod) {
  __shared__ float ws[LATENT];
  __shared__ float m2[IN_CH];
  const int b = blockIdx.x, tid = threadIdx.x;
  ws[tid] = w[b * LATENT + tid];
  ws[tid + 256] = w[b * LATENT + 256 + tid];
  __syncthreads();
  const float4* sr = (const float4*)(sw + (size_t)tid * LATENT);
  const float4* wr = (const float4*)ws;
  float s = 0.f;
#pragma unroll 8
  for (int l = 0; l < LATENT / 4; ++l) {
    float4 a = sr[l], c = wr[l];
    s += a.x * c.x + a.y * c.y + a.z * c.z + a.w * c.w;
  }
  float m = (1.0f + s + sb[tid]) * MSCALE;
  mod[b * IN_CH + tid] = m;
  m2[tid] = m * m;
  __syncthreads();
  float acc = 1e-8f;
  const float* q = wsq + (size_t)tid * IN_CH;
#pragma unroll 4
  for (int i = 0; i < IN_CH; ++i) acc += m2[i] * q[i];
  demod[b * OUT_CH + tid] = rsqrtf(acc);
}

// ---- kernel 2: wsq[o][i]=sum_9 w^2 ; wb[t][G][o][8j]=bf16(w)  (G=i>>3,j=i&7)
__global__ void k_wsq(const float* __restrict__ weight, float* __restrict__ wsq,
                      u16* __restrict__ wb) {
  const int o = blockIdx.x, i = threadIdx.x;
  const float* wp = weight + ((size_t)o * IN_CH + i) * 9;
  float s = 0.f;
#pragma unroll
  for (int t = 0; t < 9; ++t) {
    float v = wp[t];
    s += v * v;
    wb[(((size_t)t * 32 + (i >> 3)) * OUT_CH + o) * 8 + (i & 7)] = f2bf(v);
  }
  wsq[o * IN_CH + i] = s;
}

// ---- kernel 3: xs[b][pr][G][c][8j] = bf16(x*mod), zero-padded 66x66 -------
// No LDS transpose: per 16B quad, 8 lane-coalesced dword loads (one per
// channel j), *mod, f2bf, one 16B store. Pure streaming.
__global__ void k_pad(const float* __restrict__ x, const float* __restrict__ mod,
                      u16* __restrict__ xs) {
  const int bid = blockIdx.x;
  const int b = bid / 66, pr = bid - b * 66;
  const int tid = threadIdx.x;
  u16* rowbase = xs + (size_t)((b * 66 + pr) * 32) * 528;   // [32 G][66 c][8 j]

  if (pr == 0 || pr == 65) {                 // full zero row: 2112 quads of 16B
    uint4 z = {0, 0, 0, 0};
    uint4* p = (uint4*)rowbase;
#pragma unroll
    for (int it = 0; it < 9; ++it) {
      int idx = it * 256 + tid;
      if (idx < 2112) p[idx] = z;
    }
    return;
  }

  __shared__ float modsh[IN_CH];
  modsh[tid] = mod[b * IN_CH + tid];
  __syncthreads();

  const int w = tid & 63, Gq = tid >> 6;     // wave-uniform Gq
  const int h = pr - 1;
  const float* xrow = x + ((size_t)b * IN_CH * 64 + (size_t)h) * 64 + w;

  if (tid < 64) {                            // border col quads c=0, c=65
    bf16x8 z = {};
    *(bf16x8*)(rowbase + ((size_t)(tid >> 1) * 66 + (tid & 1) * 65) * 8) = z;
  }
#pragma unroll
  for (int it = 0; it < 8; ++it) {
    const int G = it * 4 + Gq;
    const float* p = xrow + (size_t)G * 8 * 4096;
    bf16x8 q;
#pragma unroll
    for (int j = 0; j < 8; ++j)
      q[j] = (short)f2bf(p[(size_t)j * 4096] * modsh[G * 8 + j]);
    *(bf16x8*)(rowbase + ((size_t)G * 66 + (w + 1)) * 8) = q;
  }
}

// ---- kernel 4: conv. R5 2-barrier dbuf structure + X-register cache.
// Per chunk/wave: 12 Xc reads (rows L1,L2 cached, reused 2x) + 12 direct (L0,L3)
// + 18 A reads = 42 ds_read_b128 feeding 72 MFMAs.
__global__ __launch_bounds__(256, 2)
void k_conv(const u16* __restrict__ xs, const u16* __restrict__ wb,
            const float* __restrict__ demod, float* __restrict__ out) {
  __shared__ __align__(16) u16 xlds[2 * 10 * 2 * 66 * 8];  // 42240 B
  __shared__ __align__(16) u16 wlds[2 * 9 * 2 * 64 * 8];   // 36864 B

  const int tid = threadIdx.x;
  const int lane = tid & 63;
  const int wid = tid >> 6;
  const int ol = lane & 31;
  const int hi = lane >> 5;

  const int bid = blockIdx.x;
  const int sbid = ((bid & 7) << 6) | (bid >> 3);  // bijective XCD swizzle (512=8*64)
  const int otile = (sbid & 3) << 6;
  const int hbase = ((sbid >> 2) & 7) << 3;
  const int b = sbid >> 5;

  const u16* xsb = xs + (size_t)((b * 66 + hbase) * 32) * 528;

  // staging source offsets (u16 units); chunk ic adds ic*1056 (X) / ic*4096 (W)
  int xoff[5];
#pragma unroll
  for (int it = 0; it < 5; ++it) {
    int q = it * 256 + tid;
    int r = q / 132, rem = q - r * 132;
    int g = rem / 66, c = rem - g * 66;
    xoff[it] = (r * 32 + g) * 528 + c * 8;
  }
  const int xofft = (9 * 32 + 1) * 528 + (26 + tid) * 8;   // q=1280+tid: r=9,g=1,c=26+tid
  int woff[4];
#pragma unroll
  for (int it = 0; it < 4; ++it) {
    int p = it * 256 + tid;
    int t = p >> 7, g = (p >> 6) & 1, o = p & 63;
    woff[it] = ((t * 32 + g) * OUT_CH + otile + o) * 8;
  }
  const int wofft = ((8 * 32 + ((tid >> 6) & 1)) * OUT_CH + otile + (tid & 63)) * 8;

  auto stage = [&](int buf, int ic) {
    const int ibx = ic * 1056;    // 2 G-groups * 528
    const int ibw = ic * 4096;    // 2 G-groups * 2048
    u16* xd = xlds + buf * 10560;
#pragma unroll
    for (int it = 0; it < 5; ++it)
      gload_lds16(xsb + xoff[it] + ibx, xd + (size_t)(it * 256 + wid * 64) * 8);
    if (tid < 40)
      gload_lds16(xsb + xofft + ibx, xd + (size_t)(1280 + wid * 64) * 8);
    u16* wd = wlds + buf * 9216;
#pragma unroll
    for (int it = 0; it < 4; ++it)
      gload_lds16(wb + woff[it] + ibw, wd + (size_t)(it * 256 + wid * 64) * 8);
    if (tid < 128)
      gload_lds16(wb + wofft + ibw, wd + (size_t)(1024 + wid * 64) * 8);
  };

  f32x16 acc[2][4] = {};

  stage(0, 0);
  __syncthreads();

  for (int ic = 0; ic < 16; ++ic) {
    const int buf = ic & 1;
    const u16* xp = xlds + buf * 10560;
    const u16* wp = wlds + buf * 9216;

    // ---- X register cache: local padded rows L1,L2 (each reused by 2 dh taps)
    bf16x8 Xc[2][6];
#pragma unroll
    for (int rr = 0; rr < 2; ++rr)
#pragma unroll
      for (int ch = 0; ch < 2; ++ch)
#pragma unroll
        for (int dw = 0; dw < 3; ++dw) {
          const int r = 2 * wid + 1 + rr;
          const int c = ch * 32 + ol + dw;
          Xc[rr][ch * 3 + dw] = *(const bf16x8*)(xp + (size_t)((r * 2 + hi) * 66 + c) * 8);
        }

    if (ic < 15) stage(buf ^ 1, ic + 1);     // prefetch next chunk (overlaps compute)

    __builtin_amdgcn_s_setprio(1);
#pragma unroll
    for (int dh = 0; dh < 3; ++dh) {
      bf16x8 A0[3], A1[3];
#pragma unroll
      for (int dw = 0; dw < 3; ++dw) {
        const int t = dh * 3 + dw;
        A0[dw] = *(const bf16x8*)(wp + (size_t)((t * 2 + hi) * 64 + ol) * 8);
        A1[dw] = *(const bf16x8*)(wp + (size_t)((t * 2 + hi) * 64 + 32 + ol) * 8);
      }
#pragma unroll
      for (int dw = 0; dw < 3; ++dw) {
#pragma unroll
        for (int ps = 0; ps < 4; ++ps) {
          const int rowoff = ps >> 1, ch = ps & 1;
          const int rl = rowoff + dh;                      // local padded row 0..3
          bf16x8 B;
          if (rl == 0 || rl == 3) {                        // direct (used once)
            const int r = 2 * wid + rl;
            const int c = ch * 32 + ol + dw;
            B = *(const bf16x8*)(xp + (size_t)((r * 2 + hi) * 66 + c) * 8);
          } else {                                         // cached (L1/L2)
            B = Xc[rl - 1][ch * 3 + dw];
          }
          acc[0][ps] = __builtin_amdgcn_mfma_f32_32x32x16_bf16(A0[dw], B, acc[0][ps], 0, 0, 0);
          acc[1][ps] = __builtin_amdgcn_mfma_f32_32x32x16_bf16(A1[dw], B, acc[1][ps], 0, 0, 0);
        }
      }
    }
    __builtin_amdgcn_s_setprio(0);
    __syncthreads();   // chunk boundary: stage loads landed; buf swap safety
  }

  // ---- epilogue: out = acc * demod[b][o]
  const float* dmb = demod + b * OUT_CH + otile;
  float* outb = out + (size_t)b * OUT_CH * 4096;
#pragma unroll
  for (int os = 0; os < 2; ++os) {
    float dm[16];
#pragma unroll
    for (int qd = 0; qd < 4; ++qd) {
      float4 d4 = *(const float4*)(dmb + os * 32 + qd * 8 + hi * 4);
      dm[qd * 4 + 0] = d4.x; dm[qd * 4 + 1] = d4.y;
      dm[qd * 4 + 2] = d4.z; dm[qd * 4 + 3] = d4.w;
    }
#pragma unroll
    for (int ps = 0; ps < 4; ++ps) {
      const int prow = hbase + 2 * wid + (ps >> 1);
      const int col = (ps & 1) * 32 + ol;
#pragma unroll
      for (int rr = 0; rr < 16; ++rr) {
        const int orow = (rr & 3) + 8 * (rr >> 2) + 4 * hi;  // C/D row map (m74/m101)
        const int o = otile + os * 32 + orow;
        outb[(size_t)o * 4096 + prow * 64 + col] = acc[os][ps][rr] * dm[rr];
      }
    }
  }
}

extern "C" void kernel_launch(void* const* d_in, const int* in_sizes, int n_in,
                              void* d_out, int out_size, void* d_ws, size_t ws_size,
                              hipStream_t stream) {
  const float* x  = (const float*)d_in[0];   // [16,256,64,64]
  const float* w  = (const float*)d_in[1];   // [16,512]
  const float* sw = (const float*)d_in[2];   // [256,512]
  const float* sb = (const float*)d_in[3];   // [256]
  const float* wt = (const float*)d_in[4];   // [1,256,256,3,3]
  float* out = (float*)d_out;

  char* ws = (char*)d_ws;
  u16*   xs    = (u16*)(ws);                  // 35,684,352 B : padded bf16 x*mod
  u16*   wbuf  = (u16*)(ws + 35684352);       //  1,179,648 B : bf16 weights [t][G][o][8]
  float* mod   = (float*)(ws + 36864000);     //     16,384 B
  float* demod = (float*)(ws + 36880384);     //     16,384 B
  float* wsq   = (float*)(ws + 36896768);     //    262,144 B   (total 37,158,912)
  if (ws_size < 37158912u) return;

  k_wsq        <<<256, 256, 0, stream>>>(wt, wsq, wbuf);
  k_style_demod<<<16, 256, 0, stream>>>(w, sw, sb, wsq, mod, demod);
  k_pad        <<<16 * 66, 256, 0, stream>>>(x, mod, xs);
  k_conv       <<<512, 256, 0, stream>>>(xs, wbuf, demod, out);
}

// Round 8
// 105.397 us; speedup vs baseline: 1.0854x; 1.0854x over previous
//
#include <hip/hip_runtime.h>
#include <hip/hip_bf16.h>

#define IN_CH 256
#define OUT_CH 256
#define LATENT 512
#define MSCALE (1.0f / 16.0f)   // 1/sqrt(256)

typedef __attribute__((ext_vector_type(8)))  short bf16x8;
typedef __attribute__((ext_vector_type(16))) float f32x16;
typedef unsigned short u16;

__device__ __forceinline__ u16 f2bf(float f) {
  unsigned int x = __float_as_uint(f);
  x += 0x7fffu + ((x >> 16) & 1u);   // round-to-nearest-even
  return (u16)(x >> 16);
}

// async global->LDS, 16B/lane; LDS dst is wave-uniform base + lane*16.
__device__ __forceinline__ void gload_lds16(const u16* g, u16* l) {
#if defined(__has_builtin) && __has_builtin(__builtin_amdgcn_global_load_lds)
  __builtin_amdgcn_global_load_lds(
      (const __attribute__((address_space(1))) unsigned int*)g,
      (__attribute__((address_space(3))) unsigned int*)l, 16, 0, 0);
#else
  int lane = __builtin_amdgcn_mbcnt_hi(~0u, __builtin_amdgcn_mbcnt_lo(~0u, 0));
  ((uint4*)l)[lane] = *(const uint4*)g;
#endif
}

// ---- kernel 1: fused prep. blocks 0..255: wsq[o][i]=sum_9 w^2, wb[t][G][o][8j].
// blocks 256..271: mod[b][i] = (1 + style + bias) * SCALE.
__global__ void k_prep(const float* __restrict__ weight, const float* __restrict__ w,
                       const float* __restrict__ sw, const float* __restrict__ sb,
                       float* __restrict__ wsq, u16* __restrict__ wb,
                       float* __restrict__ mod) {
  const int bid = blockIdx.x, tid = threadIdx.x;
  if (bid < 256) {                 // ---- wsq / wbuf part
    const int o = bid, i = tid;
    const float* wp = weight + ((size_t)o * IN_CH + i) * 9;
    float s = 0.f;
#pragma unroll
    for (int t = 0; t < 9; ++t) {
      float v = wp[t];
      s += v * v;
      wb[(((size_t)t * 32 + (i >> 3)) * OUT_CH + o) * 8 + (i & 7)] = f2bf(v);
    }
    wsq[o * IN_CH + i] = s;
  } else {                         // ---- style -> mod part
    __shared__ float ws[LATENT];
    const int b = bid - 256;
    ws[tid] = w[b * LATENT + tid];
    ws[tid + 256] = w[b * LATENT + 256 + tid];
    __syncthreads();
    const float4* sr = (const float4*)(sw + (size_t)tid * LATENT);
    const float4* wr = (const float4*)ws;
    float s = 0.f;
#pragma unroll 8
    for (int l = 0; l < LATENT / 4; ++l) {
      float4 a = sr[l], c = wr[l];
      s += a.x * c.x + a.y * c.y + a.z * c.z + a.w * c.w;
    }
    mod[b * IN_CH + tid] = (1.0f + s + sb[tid]) * MSCALE;
  }
}

// ---- kernel 2: xs[b][pr][G][c][8j] = bf16(x*mod), zero-padded 66x66.
// pr==0 border blocks also compute demod[b][o] = rsqrt(sum mod^2*wsq + 1e-8).
__global__ void k_pad(const float* __restrict__ x, const float* __restrict__ mod,
                      const float* __restrict__ wsq, u16* __restrict__ xs,
                      float* __restrict__ demod) {
  const int bid = blockIdx.x;
  const int b = bid / 66, pr = bid - b * 66;
  const int tid = threadIdx.x;
  u16* rowbase = xs + (size_t)((b * 66 + pr) * 32) * 528;   // [32 G][66 c][8 j]

  if (pr == 0 || pr == 65) {                 // full zero row: 2112 quads of 16B
    uint4 z = {0, 0, 0, 0};
    uint4* p = (uint4*)rowbase;
#pragma unroll
    for (int it = 0; it < 9; ++it) {
      int idx = it * 256 + tid;
      if (idx < 2112) p[idx] = z;
    }
    if (pr == 0) {                           // demod for this b (wsq is L2-hot)
      __shared__ float m2[IN_CH];
      float m = mod[b * IN_CH + tid];
      m2[tid] = m * m;
      __syncthreads();
      float s = 1e-8f;
      const float4* wr = (const float4*)(wsq + (size_t)tid * IN_CH);
      const float4* mq = (const float4*)m2;
#pragma unroll 4
      for (int i = 0; i < IN_CH / 4; ++i) {
        float4 a = wr[i], c = mq[i];
        s += a.x * c.x + a.y * c.y + a.z * c.z + a.w * c.w;
      }
      demod[b * OUT_CH + tid] = rsqrtf(s);
    }
    return;
  }

  __shared__ float modsh[IN_CH];
  modsh[tid] = mod[b * IN_CH + tid];
  __syncthreads();

  const int w = tid & 63, Gq = tid >> 6;     // wave-uniform Gq
  const int h = pr - 1;
  const float* xrow = x + ((size_t)b * IN_CH * 64 + (size_t)h) * 64 + w;

  if (tid < 64) {                            // border col quads c=0, c=65
    bf16x8 z = {};
    *(bf16x8*)(rowbase + ((size_t)(tid >> 1) * 66 + (tid & 1) * 65) * 8) = z;
  }
#pragma unroll
  for (int it = 0; it < 8; ++it) {
    const int G = it * 4 + Gq;
    const float* p = xrow + (size_t)G * 8 * 4096;
    bf16x8 q;
#pragma unroll
    for (int j = 0; j < 8; ++j)
      q[j] = (short)f2bf(p[(size_t)j * 4096] * modsh[G * 8 + j]);
    *(bf16x8*)(rowbase + ((size_t)G * 66 + (w + 1)) * 8) = q;
  }
}

// ---- kernel 3: conv. R7 structure; stage issued before Xc reads (longer flight).
__global__ __launch_bounds__(256, 2)
void k_conv(const u16* __restrict__ xs, const u16* __restrict__ wb,
            const float* __restrict__ demod, float* __restrict__ out) {
  __shared__ __align__(16) u16 xlds[2 * 10 * 2 * 66 * 8];  // 42240 B
  __shared__ __align__(16) u16 wlds[2 * 9 * 2 * 64 * 8];   // 36864 B

  const int tid = threadIdx.x;
  const int lane = tid & 63;
  const int wid = tid >> 6;
  const int ol = lane & 31;
  const int hi = lane >> 5;

  const int bid = blockIdx.x;
  const int sbid = ((bid & 7) << 6) | (bid >> 3);  // bijective XCD swizzle (512=8*64)
  const int otile = (sbid & 3) << 6;
  const int hbase = ((sbid >> 2) & 7) << 3;
  const int b = sbid >> 5;

  const u16* xsb = xs + (size_t)((b * 66 + hbase) * 32) * 528;

  // staging source offsets (u16 units); chunk ic adds ic*1056 (X) / ic*4096 (W)
  int xoff[5];
#pragma unroll
  for (int it = 0; it < 5; ++it) {
    int q = it * 256 + tid;
    int r = q / 132, rem = q - r * 132;
    int g = rem / 66, c = rem - g * 66;
    xoff[it] = (r * 32 + g) * 528 + c * 8;
  }
  const int xofft = (9 * 32 + 1) * 528 + (26 + tid) * 8;   // q=1280+tid: r=9,g=1,c=26+tid
  int woff[4];
#pragma unroll
  for (int it = 0; it < 4; ++it) {
    int p = it * 256 + tid;
    int t = p >> 7, g = (p >> 6) & 1, o = p & 63;
    woff[it] = ((t * 32 + g) * OUT_CH + otile + o) * 8;
  }
  const int wofft = ((8 * 32 + ((tid >> 6) & 1)) * OUT_CH + otile + (tid & 63)) * 8;

  auto stage = [&](int buf, int ic) {
    const int ibx = ic * 1056;    // 2 G-groups * 528
    const int ibw = ic * 4096;    // 2 G-groups * 2048
    u16* xd = xlds + buf * 10560;
#pragma unroll
    for (int it = 0; it < 5; ++it)
      gload_lds16(xsb + xoff[it] + ibx, xd + (size_t)(it * 256 + wid * 64) * 8);
    if (tid < 40)
      gload_lds16(xsb + xofft + ibx, xd + (size_t)(1280 + wid * 64) * 8);
    u16* wd = wlds + buf * 9216;
#pragma unroll
    for (int it = 0; it < 4; ++it)
      gload_lds16(wb + woff[it] + ibw, wd + (size_t)(it * 256 + wid * 64) * 8);
    if (tid < 128)
      gload_lds16(wb + wofft + ibw, wd + (size_t)(1024 + wid * 64) * 8);
  };

  f32x16 acc[2][4] = {};

  stage(0, 0);
  __syncthreads();

  for (int ic = 0; ic < 16; ++ic) {
    const int buf = ic & 1;
    const u16* xp = xlds + buf * 10560;
    const u16* wp = wlds + buf * 9216;

    if (ic < 15) stage(buf ^ 1, ic + 1);     // issue first: maximal load flight

    // ---- X register cache: local padded rows L1,L2 (each reused by 2 dh taps)
    bf16x8 Xc[2][6];
#pragma unroll
    for (int rr = 0; rr < 2; ++rr)
#pragma unroll
      for (int ch = 0; ch < 2; ++ch)
#pragma unroll
        for (int dw = 0; dw < 3; ++dw) {
          const int r = 2 * wid + 1 + rr;
          const int c = ch * 32 + ol + dw;
          Xc[rr][ch * 3 + dw] = *(const bf16x8*)(xp + (size_t)((r * 2 + hi) * 66 + c) * 8);
        }

    __builtin_amdgcn_s_setprio(1);
#pragma unroll
    for (int dh = 0; dh < 3; ++dh) {
      bf16x8 A0[3], A1[3];
#pragma unroll
      for (int dw = 0; dw < 3; ++dw) {
        const int t = dh * 3 + dw;
        A0[dw] = *(const bf16x8*)(wp + (size_t)((t * 2 + hi) * 64 + ol) * 8);
        A1[dw] = *(const bf16x8*)(wp + (size_t)((t * 2 + hi) * 64 + 32 + ol) * 8);
      }
#pragma unroll
      for (int dw = 0; dw < 3; ++dw) {
#pragma unroll
        for (int ps = 0; ps < 4; ++ps) {
          const int rowoff = ps >> 1, ch = ps & 1;
          const int rl = rowoff + dh;                      // local padded row 0..3
          bf16x8 B;
          if (rl == 0 || rl == 3) {                        // direct (used once)
            const int r = 2 * wid + rl;
            const int c = ch * 32 + ol + dw;
            B = *(const bf16x8*)(xp + (size_t)((r * 2 + hi) * 66 + c) * 8);
          } else {                                         // cached (L1/L2)
            B = Xc[rl - 1][ch * 3 + dw];
          }
          acc[0][ps] = __builtin_amdgcn_mfma_f32_32x32x16_bf16(A0[dw], B, acc[0][ps], 0, 0, 0);
          acc[1][ps] = __builtin_amdgcn_mfma_f32_32x32x16_bf16(A1[dw], B, acc[1][ps], 0, 0, 0);
        }
      }
    }
    __builtin_amdgcn_s_setprio(0);
    __syncthreads();   // chunk boundary: stage loads landed; buf swap safety
  }

  // ---- epilogue: out = acc * demod[b][o]
  const float* dmb = demod + b * OUT_CH + otile;
  float* outb = out + (size_t)b * OUT_CH * 4096;
#pragma unroll
  for (int os = 0; os < 2; ++os) {
    float dm[16];
#pragma unroll
    for (int qd = 0; qd < 4; ++qd) {
      float4 d4 = *(const float4*)(dmb + os * 32 + qd * 8 + hi * 4);
      dm[qd * 4 + 0] = d4.x; dm[qd * 4 + 1] = d4.y;
      dm[qd * 4 + 2] = d4.z; dm[qd * 4 + 3] = d4.w;
    }
#pragma unroll
    for (int ps = 0; ps < 4; ++ps) {
      const int prow = hbase + 2 * wid + (ps >> 1);
      const int col = (ps & 1) * 32 + ol;
#pragma unroll
      for (int rr = 0; rr < 16; ++rr) {
        const int orow = (rr & 3) + 8 * (rr >> 2) + 4 * hi;  // C/D row map (m74/m101)
        const int o = otile + os * 32 + orow;
        outb[(size_t)o * 4096 + prow * 64 + col] = acc[os][ps][rr] * dm[rr];
      }
    }
  }
}

extern "C" void kernel_launch(void* const* d_in, const int* in_sizes, int n_in,
                              void* d_out, int out_size, void* d_ws, size_t ws_size,
                              hipStream_t stream) {
  const float* x  = (const float*)d_in[0];   // [16,256,64,64]
  const float* w  = (const float*)d_in[1];   // [16,512]
  const float* sw = (const float*)d_in[2];   // [256,512]
  const float* sb = (const float*)d_in[3];   // [256]
  const float* wt = (const float*)d_in[4];   // [1,256,256,3,3]
  float* out = (float*)d_out;

  char* ws = (char*)d_ws;
  u16*   xs    = (u16*)(ws);                  // 35,684,352 B : padded bf16 x*mod
  u16*   wbuf  = (u16*)(ws + 35684352);       //  1,179,648 B : bf16 weights [t][G][o][8]
  float* mod   = (float*)(ws + 36864000);     //     16,384 B
  float* demod = (float*)(ws + 36880384);     //     16,384 B
  float* wsq   = (float*)(ws + 36896768);     //    262,144 B   (total 37,158,912)
  if (ws_size < 37158912u) return;

  k_prep<<<272, 256, 0, stream>>>(wt, w, sw, sb, wsq, wbuf, mod);
  k_pad <<<16 * 66, 256, 0, stream>>>(x, mod, wsq, xs, demod);
  k_conv<<<512, 256, 0, stream>>>(xs, wbuf, demod, out);
}

// Round 9
// 102.207 us; speedup vs baseline: 1.1193x; 1.0312x over previous
//
#include <hip/hip_runtime.h>
#include <hip/hip_bf16.h>

#define IN_CH 256
#define OUT_CH 256
#define LATENT 512
#define MSCALE (1.0f / 16.0f)   // 1/sqrt(256)

typedef __attribute__((ext_vector_type(8)))  short bf16x8;
typedef __attribute__((ext_vector_type(16))) float f32x16;
typedef unsigned short u16;
typedef unsigned int u32;

__device__ __forceinline__ u16 f2bf(float f) {
  unsigned int x = __float_as_uint(f);
  x += 0x7fffu + ((x >> 16) & 1u);   // round-to-nearest-even
  return (u16)(x >> 16);
}

// pack 2 f32 -> 2 bf16 (RNE), single instruction
__device__ __forceinline__ u32 pkbf(float lo, float hi) {
  u32 r;
  asm("v_cvt_pk_bf16_f32 %0, %1, %2" : "=v"(r) : "v"(lo), "v"(hi));
  return r;
}

// async global->LDS, 16B/lane; LDS dst is wave-uniform base + lane*16.
__device__ __forceinline__ void gload_lds16(const u16* g, u16* l) {
#if defined(__has_builtin) && __has_builtin(__builtin_amdgcn_global_load_lds)
  __builtin_amdgcn_global_load_lds(
      (const __attribute__((address_space(1))) unsigned int*)g,
      (__attribute__((address_space(3))) unsigned int*)l, 16, 0, 0);
#else
  int lane = __builtin_amdgcn_mbcnt_hi(~0u, __builtin_amdgcn_mbcnt_lo(~0u, 0));
  ((uint4*)l)[lane] = *(const uint4*)g;
#endif
}

// ---- kernel 1: fused prep. blocks 0..255: wsq[o][i]=sum_9 w^2, wb[t][G][o][8j].
// blocks 256..271: mod[b][i] = (1 + style + bias) * SCALE.
__global__ void k_prep(const float* __restrict__ weight, const float* __restrict__ w,
                       const float* __restrict__ sw, const float* __restrict__ sb,
                       float* __restrict__ wsq, u16* __restrict__ wb,
                       float* __restrict__ mod) {
  const int bid = blockIdx.x, tid = threadIdx.x;
  if (bid < 256) {                 // ---- wsq / wbuf part
    const int o = bid, i = tid;
    const float* wp = weight + ((size_t)o * IN_CH + i) * 9;
    float s = 0.f;
#pragma unroll
    for (int t = 0; t < 9; ++t) {
      float v = wp[t];
      s += v * v;
      wb[(((size_t)t * 32 + (i >> 3)) * OUT_CH + o) * 8 + (i & 7)] = f2bf(v);
    }
    wsq[o * IN_CH + i] = s;
  } else {                         // ---- style -> mod part
    __shared__ float ws[LATENT];
    const int b = bid - 256;
    ws[tid] = w[b * LATENT + tid];
    ws[tid + 256] = w[b * LATENT + 256 + tid];
    __syncthreads();
    const float4* sr = (const float4*)(sw + (size_t)tid * LATENT);
    const float4* wr = (const float4*)ws;
    float s = 0.f;
#pragma unroll 8
    for (int l = 0; l < LATENT / 4; ++l) {
      float4 a = sr[l], c = wr[l];
      s += a.x * c.x + a.y * c.y + a.z * c.z + a.w * c.w;
    }
    mod[b * IN_CH + tid] = (1.0f + s + sb[tid]) * MSCALE;
  }
}

// ---- kernel 2: fully-fused conv. X staged straight from f32 x (no xs pass):
// per chunk per thread: 40 scalar loads issued at chunk TOP (full-chunk flight),
// cvt_pk_bf16 pack + 5 ds_write_b128 committed AFTER the MFMAs. demod computed
// in prologue (t<64, wsq L2-hot) into LDS. W staged via gload_lds.
__global__ __launch_bounds__(256, 2)
void k_conv(const float* __restrict__ x, const u16* __restrict__ wb,
            const float* __restrict__ mod, const float* __restrict__ wsq,
            float* __restrict__ out) {
  __shared__ __align__(16) u16 xlds[2 * 10 * 2 * 66 * 8];  // 42240 B
  __shared__ __align__(16) u16 wlds[2 * 9 * 2 * 64 * 8];   // 36864 B
  __shared__ __align__(16) float modsh[IN_CH];             //  1024 B
  __shared__ __align__(16) float dmsh[64];                 //   256 B

  const int tid = threadIdx.x;
  const int lane = tid & 63;
  const int wid = tid >> 6;
  const int ol = lane & 31;
  const int hi = lane >> 5;

  const int bid = blockIdx.x;
  const int sbid = ((bid & 7) << 6) | (bid >> 3);  // bijective XCD swizzle (512=8*64)
  const int otile = (sbid & 3) << 6;
  const int hbase = ((sbid >> 2) & 7) << 3;
  const int b = sbid >> 5;

  // ---- X staging geometry: batch k, thread -> quad (row 2k+rhalf, g=sg, col sc1+1)
  const int sg = (tid >> 6) & 1;
  const int sc1 = tid & 63;
  const int rhalf = tid >> 7;
  const float* xb = x + (size_t)b * 1048576 + sg * 8 * 4096 + sc1;

  // ---- W staging source offsets (u16 units); chunk ic adds ic*4096
  int woff[4];
#pragma unroll
  for (int it = 0; it < 4; ++it) {
    int p = it * 256 + tid;
    int t = p >> 7, g = (p >> 6) & 1, o = p & 63;
    woff[it] = ((t * 32 + g) * OUT_CH + otile + o) * 8;
  }
  const int wofft = ((8 * 32 + ((tid >> 6) & 1)) * OUT_CH + otile + (tid & 63)) * 8;

  float va[5][8];
  float mvv[8];
  auto ldmod = [&](int ib) {
    float4 m0 = *(const float4*)(modsh + ib + sg * 8);
    float4 m1 = *(const float4*)(modsh + ib + sg * 8 + 4);
    mvv[0] = m0.x; mvv[1] = m0.y; mvv[2] = m0.z; mvv[3] = m0.w;
    mvv[4] = m1.x; mvv[5] = m1.y; mvv[6] = m1.z; mvv[7] = m1.w;
  };
  auto issueX = [&](int k, int ib, float* v) {
    const int pr = hbase + 2 * k + rhalf;
    const int hc = min(max(pr - 1, 0), 63);
    const float* p = xb + hc * 64 + (size_t)ib * 4096;
#pragma unroll
    for (int j = 0; j < 8; ++j) v[j] = p[(size_t)j * 4096];
  };
  auto commitX = [&](int k, u16* xd, const float* v) {
    const int pr = hbase + 2 * k + rhalf;
    const bool vr = (pr >= 1) && (pr <= 64);
    uint4 q;
    q.x = vr ? pkbf(v[0] * mvv[0], v[1] * mvv[1]) : 0u;
    q.y = vr ? pkbf(v[2] * mvv[2], v[3] * mvv[3]) : 0u;
    q.z = vr ? pkbf(v[4] * mvv[4], v[5] * mvv[5]) : 0u;
    q.w = vr ? pkbf(v[6] * mvv[6], v[7] * mvv[7]) : 0u;
    *(uint4*)(xd + (size_t)(((2 * k + rhalf) * 2 + sg) * 66 + sc1 + 1) * 8) = q;
  };
  auto stageW = [&](int ibw, u16* wd) {
#pragma unroll
    for (int it = 0; it < 4; ++it)
      gload_lds16(wb + woff[it] + ibw, wd + (size_t)(it * 256 + wid * 64) * 8);
    if (tid < 128)
      gload_lds16(wb + wofft + ibw, wd + (size_t)(1024 + wid * 64) * 8);
  };

  f32x16 acc[2][4] = {};

  // ---- prologue
  modsh[tid] = mod[b * IN_CH + tid];
  if (tid < 80) {   // border col quads c=0,65 of both buffers, zero once
    const int q = tid;
    const int bufz = q / 40, rem = q - bufz * 40;
    const int r = rem >> 2, g = (rem >> 1) & 1, ce = (rem & 1) * 65;
    bf16x8 z = {};
    *(bf16x8*)(xlds + (size_t)(bufz * 1320 + (r * 2 + g) * 66 + ce) * 8) = z;
  }
#pragma unroll
  for (int k = 0; k < 5; ++k) issueX(k, 0, va[k]);   // chunk-0 X loads in flight
  stageW(0, wlds);
  __syncthreads();           // modsh + border zeros visible

  if (tid < 64) {            // demod[o=otile+tid] -> dmsh (hides under load flight)
    const int o = otile + tid;
    const float4* wr = (const float4*)(wsq + (size_t)o * IN_CH);
    const float4* mq = (const float4*)modsh;
    float s = 1e-8f;
#pragma unroll 4
    for (int i = 0; i < IN_CH / 4; ++i) {
      float4 a = wr[i], c = mq[i];
      s += a.x * (c.x * c.x) + a.y * (c.y * c.y) + a.z * (c.z * c.z) + a.w * (c.w * c.w);
    }
    dmsh[tid] = rsqrtf(s);
  }
  ldmod(0);
#pragma unroll
  for (int k = 0; k < 5; ++k) commitX(k, xlds, va[k]);
  __syncthreads();           // chunk 0 staged (ds_writes + W gloads drained)

  for (int ic = 0; ic < 16; ++ic) {
    const int buf = ic & 1;
    const u16* xp = xlds + buf * 10560;
    const u16* wp = wlds + buf * 9216;
    u16* xd = xlds + (buf ^ 1) * 10560;
    u16* wd = wlds + (buf ^ 1) * 9216;
    const bool pf = (ic < 15);
    const int ib = (ic + 1) << 4;

    if (pf) {                // issue ALL next-chunk loads first: full-chunk flight
      ldmod(ib);
#pragma unroll
      for (int k = 0; k < 5; ++k) issueX(k, ib, va[k]);
      stageW((ic + 1) * 4096, wd);
    }

    __builtin_amdgcn_s_setprio(1);
#pragma unroll
    for (int dh = 0; dh < 3; ++dh) {
#pragma unroll
      for (int dw = 0; dw < 3; ++dw) {
        const int t = dh * 3 + dw;
        bf16x8 A0 = *(const bf16x8*)(wp + (size_t)((t * 2 + hi) * 64 + ol) * 8);
        bf16x8 A1 = *(const bf16x8*)(wp + (size_t)((t * 2 + hi) * 64 + 32 + ol) * 8);
#pragma unroll
        for (int ps = 0; ps < 4; ++ps) {
          const int r = 2 * wid + (ps >> 1) + dh;          // padded local row 0..9
          const int c = (ps & 1) * 32 + ol + dw;           // padded col 0..65
          bf16x8 B = *(const bf16x8*)(xp + (size_t)((r * 2 + hi) * 66 + c) * 8);
          acc[0][ps] = __builtin_amdgcn_mfma_f32_32x32x16_bf16(A0, B, acc[0][ps], 0, 0, 0);
          acc[1][ps] = __builtin_amdgcn_mfma_f32_32x32x16_bf16(A1, B, acc[1][ps], 0, 0, 0);
        }
      }
    }
    __builtin_amdgcn_s_setprio(0);

    if (pf) {                // loads had the whole MFMA window to land
#pragma unroll
      for (int k = 0; k < 5; ++k) commitX(k, xd, va[k]);
    }
    __syncthreads();         // chunk boundary: publishes staged buf, drains W gloads
  }

  // ---- epilogue: out = acc * demod (from LDS)
  float* outb = out + (size_t)b * OUT_CH * 4096;
#pragma unroll
  for (int os = 0; os < 2; ++os) {
    float dm[16];
#pragma unroll
    for (int qd = 0; qd < 4; ++qd) {
      float4 d4 = *(const float4*)(dmsh + os * 32 + qd * 8 + hi * 4);
      dm[qd * 4 + 0] = d4.x; dm[qd * 4 + 1] = d4.y;
      dm[qd * 4 + 2] = d4.z; dm[qd * 4 + 3] = d4.w;
    }
#pragma unroll
    for (int ps = 0; ps < 4; ++ps) {
      const int prow = hbase + 2 * wid + (ps >> 1);
      const int col = (ps & 1) * 32 + ol;
#pragma unroll
      for (int rr = 0; rr < 16; ++rr) {
        const int orow = (rr & 3) + 8 * (rr >> 2) + 4 * hi;  // C/D row map (m74/m101)
        const int o = otile + os * 32 + orow;
        outb[(size_t)o * 4096 + prow * 64 + col] = acc[os][ps][rr] * dm[rr];
      }
    }
  }
}

extern "C" void kernel_launch(void* const* d_in, const int* in_sizes, int n_in,
                              void* d_out, int out_size, void* d_ws, size_t ws_size,
                              hipStream_t stream) {
  const float* x  = (const float*)d_in[0];   // [16,256,64,64]
  const float* w  = (const float*)d_in[1];   // [16,512]
  const float* sw = (const float*)d_in[2];   // [256,512]
  const float* sb = (const float*)d_in[3];   // [256]
  const float* wt = (const float*)d_in[4];   // [1,256,256,3,3]
  float* out = (float*)d_out;

  char* ws = (char*)d_ws;
  u16*   wbuf  = (u16*)(ws);                  // 1,179,648 B : bf16 weights [t][G][o][8]
  float* mod   = (float*)(ws + 1179648);      //    16,384 B
  float* wsq   = (float*)(ws + 1196032);      //   262,144 B   (total 1,458,176)
  if (ws_size < 1458176u) return;

  k_prep<<<272, 256, 0, stream>>>(wt, w, sw, sb, wsq, wbuf, mod);
  k_conv<<<512, 256, 0, stream>>>(x, wbuf, mod, wsq, out);
}

// Round 10
// 100.671 us; speedup vs baseline: 1.1364x; 1.0153x over previous
//
#include <hip/hip_runtime.h>
#include <hip/hip_bf16.h>

#define IN_CH 256
#define OUT_CH 256
#define LATENT 512
#define MSCALE (1.0f / 16.0f)   // 1/sqrt(256)

typedef __attribute__((ext_vector_type(8)))  short bf16x8;
typedef __attribute__((ext_vector_type(16))) float f32x16;
typedef unsigned short u16;
typedef unsigned int u32;

__device__ __forceinline__ u16 f2bf(float f) {
  unsigned int x = __float_as_uint(f);
  x += 0x7fffu + ((x >> 16) & 1u);   // round-to-nearest-even
  return (u16)(x >> 16);
}

// pack 2 f32 -> 2 bf16 (RNE), single instruction
__device__ __forceinline__ u32 pkbf(float lo, float hi) {
  u32 r;
  asm("v_cvt_pk_bf16_f32 %0, %1, %2" : "=v"(r) : "v"(lo), "v"(hi));
  return r;
}

// async global->LDS, 16B/lane; LDS dst is wave-uniform base + lane*16.
__device__ __forceinline__ void gload_lds16(const u16* g, u16* l) {
#if defined(__has_builtin) && __has_builtin(__builtin_amdgcn_global_load_lds)
  __builtin_amdgcn_global_load_lds(
      (const __attribute__((address_space(1))) unsigned int*)g,
      (__attribute__((address_space(3))) unsigned int*)l, 16, 0, 0);
#else
  int lane = __builtin_amdgcn_mbcnt_hi(~0u, __builtin_amdgcn_mbcnt_lo(~0u, 0));
  ((uint4*)l)[lane] = *(const uint4*)g;
#endif
}

// ---- kernel 1: fused prep. blocks 0..255: wsq[o][i]=sum_9 w^2, wb[t][G][o][8j].
// blocks 256..271: mod[b][i] = (1 + style + bias) * SCALE.
__global__ void k_prep(const float* __restrict__ weight, const float* __restrict__ w,
                       const float* __restrict__ sw, const float* __restrict__ sb,
                       float* __restrict__ wsq, u16* __restrict__ wb,
                       float* __restrict__ mod) {
  const int bid = blockIdx.x, tid = threadIdx.x;
  if (bid < 256) {                 // ---- wsq / wbuf part
    const int o = bid, i = tid;
    const float* wp = weight + ((size_t)o * IN_CH + i) * 9;
    float s = 0.f;
#pragma unroll
    for (int t = 0; t < 9; ++t) {
      float v = wp[t];
      s += v * v;
      wb[(((size_t)t * 32 + (i >> 3)) * OUT_CH + o) * 8 + (i & 7)] = f2bf(v);
    }
    wsq[o * IN_CH + i] = s;
  } else {                         // ---- style -> mod part
    __shared__ float ws[LATENT];
    const int b = bid - 256;
    ws[tid] = w[b * LATENT + tid];
    ws[tid + 256] = w[b * LATENT + 256 + tid];
    __syncthreads();
    const float4* sr = (const float4*)(sw + (size_t)tid * LATENT);
    const float4* wr = (const float4*)ws;
    float s = 0.f;
#pragma unroll 8
    for (int l = 0; l < LATENT / 4; ++l) {
      float4 a = sr[l], c = wr[l];
      s += a.x * c.x + a.y * c.y + a.z * c.z + a.w * c.w;
    }
    mod[b * IN_CH + tid] = (1.0f + s + sb[tid]) * MSCALE;
  }
}

// ---- kernel 2: fused conv. X staged from f32 x with ROLLING 2-deep batches
// (R6 schedule: issue k at top / between dh groups, commit k after the next
// MFMA cluster; <=16 staging f32 live). cvt_pk_bf16 pack. demod in prologue.
__global__ __launch_bounds__(256, 2)
void k_conv(const float* __restrict__ x, const u16* __restrict__ wb,
            const float* __restrict__ mod, const float* __restrict__ wsq,
            float* __restrict__ out) {
  __shared__ __align__(16) u16 xlds[2 * 10 * 2 * 66 * 8];  // 42240 B
  __shared__ __align__(16) u16 wlds[2 * 9 * 2 * 64 * 8];   // 36864 B
  __shared__ __align__(16) float modsh[IN_CH];             //  1024 B
  __shared__ __align__(16) float dmsh[64];                 //   256 B

  const int tid = threadIdx.x;
  const int lane = tid & 63;
  const int wid = tid >> 6;
  const int ol = lane & 31;
  const int hi = lane >> 5;

  const int bid = blockIdx.x;
  const int sbid = ((bid & 7) << 6) | (bid >> 3);  // bijective XCD swizzle (512=8*64)
  const int otile = (sbid & 3) << 6;
  const int hbase = ((sbid >> 2) & 7) << 3;
  const int b = sbid >> 5;

  // ---- X staging geometry: batch k, thread -> quad (row 2k+rhalf, g=sg, col sc1+1)
  const int sg = (tid >> 6) & 1;
  const int sc1 = tid & 63;
  const int rhalf = tid >> 7;
  const float* xb = x + (size_t)b * 1048576 + sg * 8 * 4096 + sc1;

  // ---- W staging source offsets (u16 units); chunk ic adds ic*4096
  int woff[4];
#pragma unroll
  for (int it = 0; it < 4; ++it) {
    int p = it * 256 + tid;
    int t = p >> 7, g = (p >> 6) & 1, o = p & 63;
    woff[it] = ((t * 32 + g) * OUT_CH + otile + o) * 8;
  }
  const int wofft = ((8 * 32 + ((tid >> 6) & 1)) * OUT_CH + otile + (tid & 63)) * 8;

  float mvv[8];
  auto ldmod = [&](int ib) {
    float4 m0 = *(const float4*)(modsh + ib + sg * 8);
    float4 m1 = *(const float4*)(modsh + ib + sg * 8 + 4);
    mvv[0] = m0.x; mvv[1] = m0.y; mvv[2] = m0.z; mvv[3] = m0.w;
    mvv[4] = m1.x; mvv[5] = m1.y; mvv[6] = m1.z; mvv[7] = m1.w;
  };
  auto issueX = [&](int k, int ib, float* v) {
    const int pr = hbase + 2 * k + rhalf;
    const int hc = min(max(pr - 1, 0), 63);
    const float* p = xb + hc * 64 + (size_t)ib * 4096;
#pragma unroll
    for (int j = 0; j < 8; ++j) v[j] = p[(size_t)j * 4096];
  };
  auto commitX = [&](int k, u16* xd, const float* v) {
    const int pr = hbase + 2 * k + rhalf;
    const bool vr = (pr >= 1) && (pr <= 64);
    uint4 q;
    q.x = vr ? pkbf(v[0] * mvv[0], v[1] * mvv[1]) : 0u;
    q.y = vr ? pkbf(v[2] * mvv[2], v[3] * mvv[3]) : 0u;
    q.z = vr ? pkbf(v[4] * mvv[4], v[5] * mvv[5]) : 0u;
    q.w = vr ? pkbf(v[6] * mvv[6], v[7] * mvv[7]) : 0u;
    *(uint4*)(xd + (size_t)(((2 * k + rhalf) * 2 + sg) * 66 + sc1 + 1) * 8) = q;
  };
  auto stageW = [&](int ibw, u16* wd) {
#pragma unroll
    for (int it = 0; it < 4; ++it)
      gload_lds16(wb + woff[it] + ibw, wd + (size_t)(it * 256 + wid * 64) * 8);
    if (tid < 128)
      gload_lds16(wb + wofft + ibw, wd + (size_t)(1024 + wid * 64) * 8);
  };

  f32x16 acc[2][4] = {};
  float v0[8], v1[8];

  // ---- prologue
  modsh[tid] = mod[b * IN_CH + tid];
  if (tid < 80) {   // border col quads c=0,65 of both buffers, zero once
    const int q = tid;
    const int bufz = q / 40, rem = q - bufz * 40;
    const int r = rem >> 2, g = (rem >> 1) & 1, ce = (rem & 1) * 65;
    bf16x8 z = {};
    *(bf16x8*)(xlds + (size_t)(bufz * 1320 + (r * 2 + g) * 66 + ce) * 8) = z;
  }
  stageW(0, wlds);
  issueX(0, 0, v0); issueX(1, 0, v1);
  __syncthreads();           // modsh + border zeros visible

  if (tid < 64) {            // demod[o=otile+tid] -> dmsh (hides under load flight)
    const int o = otile + tid;
    const float4* wr = (const float4*)(wsq + (size_t)o * IN_CH);
    const float4* mq = (const float4*)modsh;
    float s = 1e-8f;
#pragma unroll 4
    for (int i = 0; i < IN_CH / 4; ++i) {
      float4 a = wr[i], c = mq[i];
      s += a.x * (c.x * c.x) + a.y * (c.y * c.y) + a.z * (c.z * c.z) + a.w * (c.w * c.w);
    }
    dmsh[tid] = rsqrtf(s);
  }
  ldmod(0);
  commitX(0, xlds, v0); issueX(2, 0, v0);
  commitX(1, xlds, v1); issueX(3, 0, v1);
  commitX(2, xlds, v0); issueX(4, 0, v0);
  commitX(3, xlds, v1);
  commitX(4, xlds, v0);
  __syncthreads();           // chunk 0 staged (ds_writes + W gloads drained)

  for (int ic = 0; ic < 16; ++ic) {
    const int buf = ic & 1;
    const u16* xp = xlds + buf * 10560;
    const u16* wp = wlds + buf * 9216;
    u16* xd = xlds + (buf ^ 1) * 10560;
    u16* wd = wlds + (buf ^ 1) * 9216;
    const bool pf = (ic < 15);
    const int ib = (ic + 1) << 4;

    if (pf) {                // 2-deep rolling prefetch
      ldmod(ib);
      stageW((ic + 1) * 4096, wd);
      issueX(0, ib, v0);
      issueX(1, ib, v1);
    }

#pragma unroll
    for (int dh = 0; dh < 3; ++dh) {
      __builtin_amdgcn_s_setprio(1);
#pragma unroll
      for (int dw = 0; dw < 3; ++dw) {
        const int t = dh * 3 + dw;
        bf16x8 A0 = *(const bf16x8*)(wp + (size_t)((t * 2 + hi) * 64 + ol) * 8);
        bf16x8 A1 = *(const bf16x8*)(wp + (size_t)((t * 2 + hi) * 64 + 32 + ol) * 8);
#pragma unroll
        for (int ps = 0; ps < 4; ++ps) {
          const int r = 2 * wid + (ps >> 1) + dh;          // padded local row 0..9
          const int c = (ps & 1) * 32 + ol + dw;           // padded col 0..65
          bf16x8 B = *(const bf16x8*)(xp + (size_t)((r * 2 + hi) * 66 + c) * 8);
          acc[0][ps] = __builtin_amdgcn_mfma_f32_32x32x16_bf16(A0, B, acc[0][ps], 0, 0, 0);
          acc[1][ps] = __builtin_amdgcn_mfma_f32_32x32x16_bf16(A1, B, acc[1][ps], 0, 0, 0);
        }
      }
      __builtin_amdgcn_s_setprio(0);
      if (pf) {   // commit landed loads, issue next batch (overlaps next dh)
        if (dh == 0) {
          commitX(0, xd, v0); issueX(2, ib, v0);
          commitX(1, xd, v1); issueX(3, ib, v1);
        } else if (dh == 1) {
          commitX(2, xd, v0); issueX(4, ib, v0);
          commitX(3, xd, v1);
        } else {
          commitX(4, xd, v0);
        }
      }
    }
    __syncthreads();         // chunk boundary: publishes staged buf, drains W gloads
  }

  // ---- epilogue: out = acc * demod (from LDS)
  float* outb = out + (size_t)b * OUT_CH * 4096;
#pragma unroll
  for (int os = 0; os < 2; ++os) {
    float dm[16];
#pragma unroll
    for (int qd = 0; qd < 4; ++qd) {
      float4 d4 = *(const float4*)(dmsh + os * 32 + qd * 8 + hi * 4);
      dm[qd * 4 + 0] = d4.x; dm[qd * 4 + 1] = d4.y;
      dm[qd * 4 + 2] = d4.z; dm[qd * 4 + 3] = d4.w;
    }
#pragma unroll
    for (int ps = 0; ps < 4; ++ps) {
      const int prow = hbase + 2 * wid + (ps >> 1);
      const int col = (ps & 1) * 32 + ol;
#pragma unroll
      for (int rr = 0; rr < 16; ++rr) {
        const int orow = (rr & 3) + 8 * (rr >> 2) + 4 * hi;  // C/D row map (m74/m101)
        const int o = otile + os * 32 + orow;
        outb[(size_t)o * 4096 + prow * 64 + col] = acc[os][ps][rr] * dm[rr];
      }
    }
  }
}

extern "C" void kernel_launch(void* const* d_in, const int* in_sizes, int n_in,
                              void* d_out, int out_size, void* d_ws, size_t ws_size,
                              hipStream_t stream) {
  const float* x  = (const float*)d_in[0];   // [16,256,64,64]
  const float* w  = (const float*)d_in[1];   // [16,512]
  const float* sw = (const float*)d_in[2];   // [256,512]
  const float* sb = (const float*)d_in[3];   // [256]
  const float* wt = (const float*)d_in[4];   // [1,256,256,3,3]
  float* out = (float*)d_out;

  char* ws = (char*)d_ws;
  u16*   wbuf  = (u16*)(ws);                  // 1,179,648 B : bf16 weights [t][G][o][8]
  float* mod   = (float*)(ws + 1179648);      //    16,384 B
  float* wsq   = (float*)(ws + 1196032);      //   262,144 B   (total 1,458,176)
  if (ws_size < 1458176u) return;

  k_prep<<<272, 256, 0, stream>>>(wt, w, sw, sb, wsq, wbuf, mod);
  k_conv<<<512, 256, 0, stream>>>(x, wbuf, mod, wsq, out);
}

// Round 11
// 99.252 us; speedup vs baseline: 1.1526x; 1.0143x over previous
//
#include <hip/hip_runtime.h>
#include <hip/hip_bf16.h>

#define IN_CH 256
#define OUT_CH 256
#define LATENT 512
#define MSCALE (1.0f / 16.0f)   // 1/sqrt(256)

typedef __attribute__((ext_vector_type(8)))  short bf16x8;
typedef __attribute__((ext_vector_type(16))) float f32x16;
typedef unsigned short u16;
typedef unsigned int u32;

__device__ __forceinline__ u16 f2bf(float f) {
  unsigned int x = __float_as_uint(f);
  x += 0x7fffu + ((x >> 16) & 1u);   // round-to-nearest-even
  return (u16)(x >> 16);
}

// pack 2 f32 -> 2 bf16 (RNE), single instruction
__device__ __forceinline__ u32 pkbf(float lo, float hi) {
  u32 r;
  asm("v_cvt_pk_bf16_f32 %0, %1, %2" : "=v"(r) : "v"(lo), "v"(hi));
  return r;
}

// async global->LDS, 16B/lane; LDS dst is wave-uniform base + lane*16.
__device__ __forceinline__ void gload_lds16(const u16* g, u16* l) {
#if defined(__has_builtin) && __has_builtin(__builtin_amdgcn_global_load_lds)
  __builtin_amdgcn_global_load_lds(
      (const __attribute__((address_space(1))) unsigned int*)g,
      (__attribute__((address_space(3))) unsigned int*)l, 16, 0, 0);
#else
  int lane = __builtin_amdgcn_mbcnt_hi(~0u, __builtin_amdgcn_mbcnt_lo(~0u, 0));
  ((uint4*)l)[lane] = *(const uint4*)g;
#endif
}

// ---- kernel 1: fused prep. blocks 0..255: wsq[o][i]=sum_9 w^2, wb[t][G][o][8j].
// blocks 256..271: mod[b][i] = (1 + style + bias) * SCALE.
__global__ void k_prep(const float* __restrict__ weight, const float* __restrict__ w,
                       const float* __restrict__ sw, const float* __restrict__ sb,
                       float* __restrict__ wsq, u16* __restrict__ wb,
                       float* __restrict__ mod) {
  const int bid = blockIdx.x, tid = threadIdx.x;
  if (bid < 256) {                 // ---- wsq / wbuf part
    const int o = bid, i = tid;
    const float* wp = weight + ((size_t)o * IN_CH + i) * 9;
    float s = 0.f;
#pragma unroll
    for (int t = 0; t < 9; ++t) {
      float v = wp[t];
      s += v * v;
      wb[(((size_t)t * 32 + (i >> 3)) * OUT_CH + o) * 8 + (i & 7)] = f2bf(v);
    }
    wsq[o * IN_CH + i] = s;
  } else {                         // ---- style -> mod part
    __shared__ float ws[LATENT];
    const int b = bid - 256;
    ws[tid] = w[b * LATENT + tid];
    ws[tid + 256] = w[b * LATENT + 256 + tid];
    __syncthreads();
    const float4* sr = (const float4*)(sw + (size_t)tid * LATENT);
    const float4* wr = (const float4*)ws;
    float s = 0.f;
#pragma unroll 8
    for (int l = 0; l < LATENT / 4; ++l) {
      float4 a = sr[l], c = wr[l];
      s += a.x * c.x + a.y * c.y + a.z * c.z + a.w * c.w;
    }
    mod[b * IN_CH + tid] = (1.0f + s + sb[tid]) * MSCALE;
  }
}

// ---- kernel 2: fused conv. X staged from f32 x via float2 column-pair gathers:
// thread -> (rbase=tid>>6, g=(tid>>5)&1, c2=tid&31); slots r=rbase,+4,+8(tid<128).
// Per slot: 8 float2 loads (256B-coalesced), cvt_pk pack, 2 ds_write_b128.
// 1-deep rolling issue/commit between dh MFMA clusters. demod in prologue.
__global__ __launch_bounds__(256, 2)
void k_conv(const float* __restrict__ x, const u16* __restrict__ wb,
            const float* __restrict__ mod, const float* __restrict__ wsq,
            float* __restrict__ out) {
  __shared__ __align__(16) u16 xlds[2 * 10 * 2 * 66 * 8];  // 42240 B
  __shared__ __align__(16) u16 wlds[2 * 9 * 2 * 64 * 8];   // 36864 B
  __shared__ __align__(16) float modsh[IN_CH];             //  1024 B
  __shared__ __align__(16) float dmsh[64];                 //   256 B

  const int tid = threadIdx.x;
  const int lane = tid & 63;
  const int wid = tid >> 6;
  const int ol = lane & 31;
  const int hi = lane >> 5;

  const int bid = blockIdx.x;
  const int sbid = ((bid & 7) << 6) | (bid >> 3);  // bijective XCD swizzle (512=8*64)
  const int otile = (sbid & 3) << 6;
  const int hbase = ((sbid >> 2) & 7) << 3;
  const int b = sbid >> 5;

  // ---- X staging geometry (column-pair gathers)
  const int rbase = tid >> 6;            // wave-uniform row base 0..3
  const int g2 = (tid >> 5) & 1;         // k-halfgroup
  const int c2 = tid & 31;               // column pair: cols 1+2*c2, 2+2*c2
  const float* xb2 = x + (size_t)b * 1048576 + (size_t)g2 * 8 * 4096 + 2 * c2;

  // ---- W staging source offsets (u16 units); chunk ic adds ic*4096
  int woff[4];
#pragma unroll
  for (int it = 0; it < 4; ++it) {
    int p = it * 256 + tid;
    int t = p >> 7, g = (p >> 6) & 1, o = p & 63;
    woff[it] = ((t * 32 + g) * OUT_CH + otile + o) * 8;
  }
  const int wofft = ((8 * 32 + ((tid >> 6) & 1)) * OUT_CH + otile + (tid & 63)) * 8;

  float mvv[8];
  auto ldmod = [&](int ib) {
    float4 m0 = *(const float4*)(modsh + ib + g2 * 8);
    float4 m1 = *(const float4*)(modsh + ib + g2 * 8 + 4);
    mvv[0] = m0.x; mvv[1] = m0.y; mvv[2] = m0.z; mvv[3] = m0.w;
    mvv[4] = m1.x; mvv[5] = m1.y; mvv[6] = m1.z; mvv[7] = m1.w;
  };
  // issue slot r: v[2j]=ch j col c, v[2j+1]=ch j col c+1
  auto issueX = [&](int r, int iboff, float* v) {
    const int pr = hbase + r;
    const int hc = min(max(pr - 1, 0), 63);
    const float* p = xb2 + (size_t)iboff * 4096 + hc * 64;
#pragma unroll
    for (int j = 0; j < 8; ++j) {
      float2 t2 = *(const float2*)(p + (size_t)j * 4096);
      v[2 * j] = t2.x; v[2 * j + 1] = t2.y;
    }
  };
  auto commitX = [&](int r, u16* xd, const float* v) {
    const int pr = hbase + r;
    const bool vr = (pr >= 1) && (pr <= 64);   // wave-uniform
    uint4 qa, qb;
    qa.x = vr ? pkbf(v[0]  * mvv[0], v[2]  * mvv[1]) : 0u;
    qa.y = vr ? pkbf(v[4]  * mvv[2], v[6]  * mvv[3]) : 0u;
    qa.z = vr ? pkbf(v[8]  * mvv[4], v[10] * mvv[5]) : 0u;
    qa.w = vr ? pkbf(v[12] * mvv[6], v[14] * mvv[7]) : 0u;
    qb.x = vr ? pkbf(v[1]  * mvv[0], v[3]  * mvv[1]) : 0u;
    qb.y = vr ? pkbf(v[5]  * mvv[2], v[7]  * mvv[3]) : 0u;
    qb.z = vr ? pkbf(v[9]  * mvv[4], v[11] * mvv[5]) : 0u;
    qb.w = vr ? pkbf(v[13] * mvv[6], v[15] * mvv[7]) : 0u;
    u16* base = xd + (size_t)((r * 2 + g2) * 66 + 1 + 2 * c2) * 8;
    *(uint4*)base = qa;
    *(uint4*)(base + 8) = qb;
  };
  auto stageW = [&](int ibw, u16* wd) {
#pragma unroll
    for (int it = 0; it < 4; ++it)
      gload_lds16(wb + woff[it] + ibw, wd + (size_t)(it * 256 + wid * 64) * 8);
    if (tid < 128)
      gload_lds16(wb + wofft + ibw, wd + (size_t)(1024 + wid * 64) * 8);
  };

  f32x16 acc[2][4] = {};
  float va[16], vb[16];

  // ---- prologue
  modsh[tid] = mod[b * IN_CH + tid];
  if (tid < 80) {   // border col quads c=0,65 of both buffers, zero once
    const int q = tid;
    const int bufz = q / 40, rem = q - bufz * 40;
    const int r = rem >> 2, g = (rem >> 1) & 1, ce = (rem & 1) * 65;
    bf16x8 z = {};
    *(bf16x8*)(xlds + (size_t)(bufz * 1320 + (r * 2 + g) * 66 + ce) * 8) = z;
  }
  stageW(0, wlds);
  issueX(rbase, 0, va);
  __syncthreads();           // modsh + border zeros visible

  if (tid < 64) {            // demod[o=otile+tid] -> dmsh (hides under load flight)
    const int o = otile + tid;
    const float4* wr = (const float4*)(wsq + (size_t)o * IN_CH);
    const float4* mq = (const float4*)modsh;
    float s = 1e-8f;
#pragma unroll 4
    for (int i = 0; i < IN_CH / 4; ++i) {
      float4 a = wr[i], c = mq[i];
      s += a.x * (c.x * c.x) + a.y * (c.y * c.y) + a.z * (c.z * c.z) + a.w * (c.w * c.w);
    }
    dmsh[tid] = rsqrtf(s);
  }
  ldmod(0);
  commitX(rbase, xlds, va);
  issueX(rbase + 4, 0, vb);
  commitX(rbase + 4, xlds, vb);
  if (tid < 128) { issueX(rbase + 8, 0, va); commitX(rbase + 8, xlds, va); }
  __syncthreads();           // chunk 0 staged (ds_writes + W gloads drained)

  for (int ic = 0; ic < 16; ++ic) {
    const int buf = ic & 1;
    const u16* xp = xlds + buf * 10560;
    const u16* wp = wlds + buf * 9216;
    u16* xd = xlds + (buf ^ 1) * 10560;
    u16* wd = wlds + (buf ^ 1) * 9216;
    const bool pf = (ic < 15);
    const int ib = (ic + 1) << 4;

    if (pf) {                // issue slot 0 + W for next chunk
      ldmod(ib);
      stageW((ic + 1) * 4096, wd);
      issueX(rbase, ib, va);
    }

#pragma unroll
    for (int dh = 0; dh < 3; ++dh) {
      __builtin_amdgcn_s_setprio(1);
#pragma unroll
      for (int dw = 0; dw < 3; ++dw) {
        const int t = dh * 3 + dw;
        bf16x8 A0 = *(const bf16x8*)(wp + (size_t)((t * 2 + hi) * 64 + ol) * 8);
        bf16x8 A1 = *(const bf16x8*)(wp + (size_t)((t * 2 + hi) * 64 + 32 + ol) * 8);
#pragma unroll
        for (int ps = 0; ps < 4; ++ps) {
          const int r = 2 * wid + (ps >> 1) + dh;          // padded local row 0..9
          const int c = (ps & 1) * 32 + ol + dw;           // padded col 0..65
          bf16x8 B = *(const bf16x8*)(xp + (size_t)((r * 2 + hi) * 66 + c) * 8);
          acc[0][ps] = __builtin_amdgcn_mfma_f32_32x32x16_bf16(A0, B, acc[0][ps], 0, 0, 0);
          acc[1][ps] = __builtin_amdgcn_mfma_f32_32x32x16_bf16(A1, B, acc[1][ps], 0, 0, 0);
        }
      }
      __builtin_amdgcn_s_setprio(0);
      if (pf) {   // commit landed slot, issue next (flight = one dh cluster)
        if (dh == 0) {
          commitX(rbase, xd, va);
          issueX(rbase + 4, ib, vb);
        } else if (dh == 1) {
          commitX(rbase + 4, xd, vb);
          if (tid < 128) issueX(rbase + 8, ib, va);
        } else {
          if (tid < 128) commitX(rbase + 8, xd, va);
        }
      }
    }
    __syncthreads();         // chunk boundary: publishes staged buf, drains W gloads
  }

  // ---- epilogue: out = acc * demod (from LDS)
  float* outb = out + (size_t)b * OUT_CH * 4096;
#pragma unroll
  for (int os = 0; os < 2; ++os) {
    float dm[16];
#pragma unroll
    for (int qd = 0; qd < 4; ++qd) {
      float4 d4 = *(const float4*)(dmsh + os * 32 + qd * 8 + hi * 4);
      dm[qd * 4 + 0] = d4.x; dm[qd * 4 + 1] = d4.y;
      dm[qd * 4 + 2] = d4.z; dm[qd * 4 + 3] = d4.w;
    }
#pragma unroll
    for (int ps = 0; ps < 4; ++ps) {
      const int prow = hbase + 2 * wid + (ps >> 1);
      const int col = (ps & 1) * 32 + ol;
#pragma unroll
      for (int rr = 0; rr < 16; ++rr) {
        const int orow = (rr & 3) + 8 * (rr >> 2) + 4 * hi;  // C/D row map (m74/m101)
        const int o = otile + os * 32 + orow;
        outb[(size_t)o * 4096 + prow * 64 + col] = acc[os][ps][rr] * dm[rr];
      }
    }
  }
}

extern "C" void kernel_launch(void* const* d_in, const int* in_sizes, int n_in,
                              void* d_out, int out_size, void* d_ws, size_t ws_size,
                              hipStream_t stream) {
  const float* x  = (const float*)d_in[0];   // [16,256,64,64]
  const float* w  = (const float*)d_in[1];   // [16,512]
  const float* sw = (const float*)d_in[2];   // [256,512]
  const float* sb = (const float*)d_in[3];   // [256]
  const float* wt = (const float*)d_in[4];   // [1,256,256,3,3]
  float* out = (float*)d_out;

  char* ws = (char*)d_ws;
  u16*   wbuf  = (u16*)(ws);                  // 1,179,648 B : bf16 weights [t][G][o][8]
  float* mod   = (float*)(ws + 1179648);      //    16,384 B
  float* wsq   = (float*)(ws + 1196032);      //   262,144 B   (total 1,458,176)
  if (ws_size < 1458176u) return;

  k_prep<<<272, 256, 0, stream>>>(wt, w, sw, sb, wsq, wbuf, mod);
  k_conv<<<512, 256, 0, stream>>>(x, wbuf, mod, wsq, out);
}